// Round 2
// 131.555 us; speedup vs baseline: 1.0225x; 1.0225x over previous
//
#include <hip/hip_runtime.h>
#include <hip/hip_bf16.h>

// B=8, NH=8, KS=VS=64, HW=1024, C=1536, GROUPS=24. pair = b*8+h (64 pairs).
// gn_partial -> pack (Qn/Kn [s][c], Vn [c][s], bf16) -> attn:
//   attn uses 32x32x16 MFMA; P stays in-register via permlane32_swap
//   (no PT LDS round-trip). K/V tiles staged to LDS (XOR-swizzled,
//   conflict-free ds_read_b128), register prefetch of next tile under
//   compute, one barrier per tile. Fixed-offset softmax.

typedef __attribute__((ext_vector_type(8))) short bf16x8;
typedef __attribute__((ext_vector_type(4))) float f32x4;
typedef __attribute__((ext_vector_type(16))) float f32x16;
typedef unsigned short u16;
typedef unsigned int u32;

#define SM_SCALE 0.18033688f   // 0.125 * log2(e)
#define SM_OFF   8.0f          // fixed softmax offset (shift-invariant)

__device__ __forceinline__ u32 pack2(float a, float b) {  // (bf(b)<<16)|bf(a)
    union { float f; u32 u; } ua, ub; ua.f = a; ub.f = b;
    return __builtin_amdgcn_perm(ub.u + 0x8000u, ua.u + 0x8000u, 0x07060302u);
}
union BB { uint4 u; bf16x8 v; };

__device__ __forceinline__ f32x16 zero16() {
    f32x16 z;
#pragma unroll
    for (int i = 0; i < 16; ++i) z[i] = 0.f;
    return z;
}

// v_permlane32_swap_b32(a, b): a.upper ⇄ b.lower.
//   ret0 = {lane<32: own a,            lane>=32: b from lane-32}
//   ret1 = {lane<32: a from lane+32,   lane>=32: own b}
__device__ __forceinline__ void swap32(u32 a, u32 b, int hi, u32& ret0, u32& ret1) {
#if __has_builtin(__builtin_amdgcn_permlane32_swap)
    (void)hi;
    auto sw = __builtin_amdgcn_permlane32_swap(a, b, false, false);
    ret0 = sw[0]; ret1 = sw[1];
#else
    u32 pa = __shfl_xor(a, 32), pb = __shfl_xor(b, 32);
    ret0 = hi ? pb : a;
    ret1 = hi ? b : pa;
#endif
}

// ---- Kernel 1: partial GN stats. 1536 blocks = 8 slices per (b,group).
__global__ __launch_bounds__(256) void gn_partial(const float* __restrict__ x,
                                                  float* __restrict__ partials) {
    int blk = blockIdx.x;
    const float4* p = (const float4*)(x + (size_t)blk * 8192);
    int t = threadIdx.x;
    float s1a = 0.f, s2a = 0.f, s1b = 0.f, s2b = 0.f;
#pragma unroll
    for (int i = 0; i < 8; i += 2) {
        float4 va = p[t + i * 256];
        float4 vb = p[t + (i + 1) * 256];
        s1a += va.x + va.y + va.z + va.w;
        s2a += va.x*va.x + va.y*va.y + va.z*va.z + va.w*va.w;
        s1b += vb.x + vb.y + vb.z + vb.w;
        s2b += vb.x*vb.x + vb.y*vb.y + vb.z*vb.z + vb.w*vb.w;
    }
    float s1 = s1a + s1b, s2 = s2a + s2b;
    for (int off = 32; off > 0; off >>= 1) {
        s1 += __shfl_down(s1, off);
        s2 += __shfl_down(s2, off);
    }
    __shared__ float a1[4], a2[4];
    int wave = t >> 6, lane = t & 63;
    if (lane == 0) { a1[wave] = s1; a2[wave] = s2; }
    __syncthreads();
    if (t == 0) {
        partials[blk * 2 + 0] = a1[0] + a1[1] + a1[2] + a1[3];
        partials[blk * 2 + 1] = a2[0] + a2[1] + a2[2] + a2[3];
    }
}

__device__ __forceinline__ void group_stats(const float* __restrict__ partials,
                                            int bg, float& mean, float& rstd) {
    float s1 = 0.f, s2 = 0.f;
#pragma unroll
    for (int j = 0; j < 8; ++j) {
        s1 += partials[(bg * 8 + j) * 2 + 0];
        s2 += partials[(bg * 8 + j) * 2 + 1];
    }
    mean = s1 * (1.f / 65536.f);
    float var = s2 * (1.f / 65536.f) - mean * mean;
    rstd = rsqrtf(var + 1e-5f);
}

// ---- Kernel 2: normalize + pack. Coalesced x loads; K,Q -> [s][c] via
// paired-u32 LDS transpose (odd stride = conflict-free); V -> [c][s] direct.
__global__ __launch_bounds__(256) void pack_kernel(
    const float* __restrict__ x, const float* __restrict__ gamma,
    const float* __restrict__ beta, const float* __restrict__ partials,
    u16* __restrict__ Qn, u16* __restrict__ Kn, u16* __restrict__ Vn)
{
    const int st = blockIdx.x >> 6, pair = blockIdx.x & 63;
    const int b = pair >> 3, h = pair & 7;
    const float* xb = x + (size_t)b * 1536 * 1024;
    float ms[3], rs[3];
    group_stats(partials, b * 24 + 3 * h + 0, ms[0], rs[0]);
    group_stats(partials, b * 24 + 3 * h + 1, ms[1], rs[1]);
    group_stats(partials, b * 24 + 3 * h + 2, ms[2], rs[2]);

    const int t = threadIdx.x;
    __shared__ u32 Tsh[64][33];

    const int cp = t >> 4;          // 0..15 channel-pair
    const int s4 = (t & 15) * 4;
    const int sgl = st * 64 + s4;

    for (int t2 = 0; t2 < 2; ++t2) {       // K then Q
        if (t2) __syncthreads();
#pragma unroll
        for (int dc = 0; dc < 2; ++dc) {
            int cg0 = h * 192 + t2 * 64 + dc * 32 + cp * 2;
            float4 va = *(const float4*)(xb + (size_t)cg0 * 1024 + sgl);
            float4 vb = *(const float4*)(xb + (size_t)(cg0 + 1) * 1024 + sgl);
            float w0 = gamma[cg0] * rs[t2],     b0 = beta[cg0] - ms[t2] * w0;
            float w1 = gamma[cg0 + 1] * rs[t2], b1 = beta[cg0 + 1] - ms[t2] * w1;
            int col = dc * 16 + cp;
            Tsh[s4 + 0][col] = pack2(va.x * w0 + b0, vb.x * w1 + b1);
            Tsh[s4 + 1][col] = pack2(va.y * w0 + b0, vb.y * w1 + b1);
            Tsh[s4 + 2][col] = pack2(va.z * w0 + b0, vb.z * w1 + b1);
            Tsh[s4 + 3][col] = pack2(va.w * w0 + b0, vb.w * w1 + b1);
        }
        __syncthreads();
        u16* dst = (t2 ? Qn : Kn) + (size_t)pair * 65536 + (size_t)st * 64 * 64;
#pragma unroll
        for (int p = 0; p < 2; ++p) {
            int row = p * 32 + (t >> 3);
            int c8 = (t & 7) * 4;
            uint4 o;
            o.x = Tsh[row][c8 + 0]; o.y = Tsh[row][c8 + 1];
            o.z = Tsh[row][c8 + 2]; o.w = Tsh[row][c8 + 3];
            *(uint4*)(dst + (size_t)row * 64 + c8 * 2) = o;
        }
    }
    // V: native [c][s], no LDS.
    {
#pragma unroll
        for (int dc = 0; dc < 4; ++dc) {
            int c = dc * 16 + (t >> 4);
            int cg = h * 192 + 128 + c;
            float4 v = *(const float4*)(xb + (size_t)cg * 1024 + sgl);
            float wsc = gamma[cg] * rs[2];
            float bsc = beta[cg] - ms[2] * wsc;
            uint2 o;
            o.x = pack2(v.x * wsc + bsc, v.y * wsc + bsc);
            o.y = pack2(v.z * wsc + bsc, v.w * wsc + bsc);
            *(uint2*)(Vn + (size_t)pair * 65536 + (size_t)c * 1024 + sgl) = o;
        }
    }
}

// ---- Kernel 3: flash attention, 32x32x16 MFMA, in-register P.
// Grid 512: bid = qt*64 + pair (qt 0..7) -> blocks of one pair share an XCD.
// Block = 256 thr = 4 waves; block owns 128 queries (32/wave). Per K-tile:
// prefetch next tile into 4 staging uint4/thread, compute current from LDS.
// Wave layout: li = lane&31 = q column, hi = lane>>5.
//   QK^T: A=K[m=key][k=c] (2 kf x 4 cs), B=Q[n=q][k=c] -> S^T[key][q].
//   S^T C-layout: col=q=li, row(reg,hi) = (reg&3)+8*(reg>>2)+4*hi.
//   Per lane & 16-key block ks=2*kf+s: p0..p3 = key-offsets 4hi+{0..3},
//   p4..p7 = 4hi+8+{0..3}. PV B-operand needs offsets 8hi+{0..7}:
//   exactly one permlane32_swap per packed u32 pair:
//     swap32(Pa,Pc) -> (w0,w2), swap32(Pb,Pd) -> (w1,w3).
__global__ __launch_bounds__(256, 2) void attn_kernel(
    const u16* __restrict__ Qn, const u16* __restrict__ Kn,
    const u16* __restrict__ Vn, float* __restrict__ out)
{
    const int bid = blockIdx.x;
    const int qt = bid >> 6;        // 0..7
    const int pair = bid & 63;
    const int tid = threadIdx.x;
    const int w = tid >> 6;
    const int lane = tid & 63;
    const int li = lane & 31;       // q within wave tile
    const int hi = lane >> 5;

    __shared__ uint4 KT[2][512];            // [buf][row*8 + (chunk^(row&7))]
    __shared__ uint4 VT[2][512];

    const u16* Qp = Qn + (size_t)pair * 65536;
    const u16* Kp = Kn + (size_t)pair * 65536;
    const u16* Vp = Vn + (size_t)pair * 65536;

    // staging geometry: thread t covers 16B chunks j = 2t, 2t+1 (512 total)
    const int j0 = tid * 2;
    const int srow = j0 >> 3;               // 0..63
    const int sch  = j0 & 7;                // even
    const int sx   = srow & 7;
    const int idx0 = srow * 8 + (sch ^ sx);
    const int idx1 = srow * 8 + ((sch + 1) ^ sx);

    // Q B-frags: B[n=q=li][k=c = cs*16 + hi*8 + j]
    const int q0 = qt * 128 + w * 32;
    bf16x8 bq[4];
#pragma unroll
    for (int cs = 0; cs < 4; ++cs)
        bq[cs] = *(const bf16x8*)(Qp + (size_t)(q0 + li) * 64 + cs * 16 + hi * 8);

    f32x16 oacc[2];
    oacc[0] = zero16(); oacc[1] = zero16();
    float lsum = 0.f;

    const int x7 = li & 7;                  // (row&7) for rows kf*32+li / vf*32+li

    // ---- prologue: stage tile 0
    uint4 s0, s1, s2, s3;
    s0 = *(const uint4*)(Kp + (size_t)j0 * 8);
    s1 = *(const uint4*)(Kp + (size_t)j0 * 8 + 8);
    s2 = *(const uint4*)(Vp + (size_t)srow * 1024 + sch * 8);
    s3 = *(const uint4*)(Vp + (size_t)srow * 1024 + sch * 8 + 8);
    KT[0][idx0] = s0; KT[0][idx1] = s1;
    VT[0][idx0] = s2; VT[0][idx1] = s3;
    __syncthreads();

#pragma unroll 2
    for (int kt = 0; kt < 16; ++kt) {
        const int cur = kt & 1;
        // ---- issue next tile's staging loads (covered by this tile's compute)
        if (kt < 15) {
            s0 = *(const uint4*)(Kp + (size_t)(kt + 1) * 4096 + j0 * 8);
            s1 = *(const uint4*)(Kp + (size_t)(kt + 1) * 4096 + j0 * 8 + 8);
            s2 = *(const uint4*)(Vp + (size_t)srow * 1024 + (kt + 1) * 64 + sch * 8);
            s3 = *(const uint4*)(Vp + (size_t)srow * 1024 + (kt + 1) * 64 + sch * 8 + 8);
        }

        // ---- S^T = K Q^T : 2 key-blocks of 32, accumulate over 4 c-steps
        f32x16 sf[2];
#pragma unroll
        for (int kf = 0; kf < 2; ++kf) {
            bf16x8 ak[4];
#pragma unroll
            for (int cs = 0; cs < 4; ++cs)
                ak[cs] = ((const BB*)&KT[cur][(kf * 32 + li) * 8 + ((cs * 2 + hi) ^ x7)])->v;
            f32x16 acc = zero16();
            __builtin_amdgcn_s_setprio(1);
#pragma unroll
            for (int cs = 0; cs < 4; ++cs)
                acc = __builtin_amdgcn_mfma_f32_32x32x16_bf16(ak[cs], bq[cs], acc, 0, 0, 0);
            __builtin_amdgcn_s_setprio(0);
            sf[kf] = acc;
        }

        // ---- P = exp2(s*scale - OFF); pack to bf16 + partner swap -> PV B-frags.
        // pbv[ks=2*kf+s] holds keys (within tile) ks*16 + hi*8 + {0..7}, q=li.
        BB pbv[4];
#pragma unroll
        for (int kf = 0; kf < 2; ++kf)
#pragma unroll
            for (int s = 0; s < 2; ++s) {
                float p0 = exp2f(__builtin_fmaf(sf[kf][8 * s + 0], SM_SCALE, -SM_OFF));
                float p1 = exp2f(__builtin_fmaf(sf[kf][8 * s + 1], SM_SCALE, -SM_OFF));
                float p2 = exp2f(__builtin_fmaf(sf[kf][8 * s + 2], SM_SCALE, -SM_OFF));
                float p3 = exp2f(__builtin_fmaf(sf[kf][8 * s + 3], SM_SCALE, -SM_OFF));
                float p4 = exp2f(__builtin_fmaf(sf[kf][8 * s + 4], SM_SCALE, -SM_OFF));
                float p5 = exp2f(__builtin_fmaf(sf[kf][8 * s + 5], SM_SCALE, -SM_OFF));
                float p6 = exp2f(__builtin_fmaf(sf[kf][8 * s + 6], SM_SCALE, -SM_OFF));
                float p7 = exp2f(__builtin_fmaf(sf[kf][8 * s + 7], SM_SCALE, -SM_OFF));
                lsum += ((p0 + p1) + (p2 + p3)) + ((p4 + p5) + (p6 + p7));
                u32 Pa = pack2(p0, p1), Pb = pack2(p2, p3);
                u32 Pc = pack2(p4, p5), Pd = pack2(p6, p7);
                u32 w0, w1, w2, w3;
                swap32(Pa, Pc, hi, w0, w2);   // w0=offs 8hi+{0,1}, w2=8hi+{4,5}
                swap32(Pb, Pd, hi, w1, w3);   // w1=offs 8hi+{2,3}, w3=8hi+{6,7}
                pbv[kf * 2 + s].u = uint4{w0, w1, w2, w3};
            }

        // ---- O^T += V P : A=V[m=v][k=key] (2 vf x 4 ks), B=P
#pragma unroll
        for (int vf = 0; vf < 2; ++vf) {
            bf16x8 av[4];
#pragma unroll
            for (int ks = 0; ks < 4; ++ks)
                av[ks] = ((const BB*)&VT[cur][(vf * 32 + li) * 8 + ((ks * 2 + hi) ^ x7)])->v;
            __builtin_amdgcn_s_setprio(1);
#pragma unroll
            for (int ks = 0; ks < 4; ++ks)
                oacc[vf] = __builtin_amdgcn_mfma_f32_32x32x16_bf16(av[ks], pbv[ks].v, oacc[vf], 0, 0, 0);
            __builtin_amdgcn_s_setprio(0);
        }

        // ---- commit staged tile, one barrier per iteration
        if (kt < 15) {
            const int nxt = cur ^ 1;
            KT[nxt][idx0] = s0; KT[nxt][idx1] = s1;
            VT[nxt][idx0] = s2; VT[nxt][idx1] = s3;
        }
        __syncthreads();
    }

    // ---- epilogue: l covers own hi-half key offsets; partner holds the rest.
    lsum += __shfl_xor(lsum, 32);
    float invl = 1.f / lsum;
    float* ob = out + (size_t)pair * 65536 + q0 + li;
#pragma unroll
    for (int vf = 0; vf < 2; ++vf)
#pragma unroll
        for (int r = 0; r < 16; ++r) {
            int v = vf * 32 + (r & 3) + 8 * (r >> 2) + 4 * hi;
            ob[(size_t)v * 1024] = oacc[vf][r] * invl;
        }
}

extern "C" void kernel_launch(void* const* d_in, const int* in_sizes, int n_in,
                              void* d_out, int out_size, void* d_ws, size_t ws_size,
                              hipStream_t stream) {
    const float* x     = (const float*)d_in[0];
    const float* gamma = (const float*)d_in[1];
    const float* beta  = (const float*)d_in[2];
    float* out = (float*)d_out;

    float* partials = (float*)d_ws;                       // 3072 f32
    u16* Qn = (u16*)((char*)d_ws + 32768);                // 8.4 MB
    u16* Kn = Qn + (size_t)64 * 65536;                    // 8.4 MB
    u16* Vn = Kn + (size_t)64 * 65536;                    // 8.4 MB (~25.2 MB total)

    gn_partial<<<1536, 256, 0, stream>>>(x, partials);
    pack_kernel<<<1024, 256, 0, stream>>>(x, gamma, beta, partials, Qn, Kn, Vn);
    attn_kernel<<<512, 256, 0, stream>>>(Qn, Kn, Vn, out);
}

// Round 4
// 129.638 us; speedup vs baseline: 1.0376x; 1.0148x over previous
//
#include <hip/hip_runtime.h>
#include <hip/hip_bf16.h>

// B=8, NH=8, KS=VS=64, HW=1024, C=1536, GROUPS=24. pair = b*8+h (64 pairs).
// gn_partial (stats) -> attn_fused: normalize+pack happens INSIDE the attn
// kernel's staging slot (raw x -> swizzled KT/VT LDS tiles + Q in registers);
// no Qn/Kn/Vn intermediate, no pack kernel. attn: 32x32x16 MFMA, P in-register
// via permlane32_swap, XOR-swizzled LDS (conflict-free ds_read_b128),
// prefetch-early/commit-late staging, one barrier per tile, fixed-offset
// softmax. MFMA read-side is byte-identical to the verified round-2 kernel.

typedef __attribute__((ext_vector_type(8))) short bf16x8;
typedef __attribute__((ext_vector_type(4))) float f32x4;
typedef __attribute__((ext_vector_type(16))) float f32x16;
typedef unsigned short u16;
typedef unsigned int u32;

#define SM_SCALE 0.18033688f   // 0.125 * log2(e)
#define SM_OFF   8.0f          // fixed softmax offset (shift-invariant)

__device__ __forceinline__ u32 pack2(float a, float b) {  // (bf(b)<<16)|bf(a)
    union { float f; u32 u; } ua, ub; ua.f = a; ub.f = b;
    return __builtin_amdgcn_perm(ub.u + 0x8000u, ua.u + 0x8000u, 0x07060302u);
}
union BB { uint4 u; bf16x8 v; };

__device__ __forceinline__ f32x16 zero16() {
    f32x16 z;
#pragma unroll
    for (int i = 0; i < 16; ++i) z[i] = 0.f;
    return z;
}

// v_permlane32_swap_b32(a, b): a.upper ⇄ b.lower.
//   ret0 = {lane<32: own a,            lane>=32: b from lane-32}
//   ret1 = {lane<32: a from lane+32,   lane>=32: own b}
__device__ __forceinline__ void swap32(u32 a, u32 b, int hi, u32& ret0, u32& ret1) {
#if __has_builtin(__builtin_amdgcn_permlane32_swap)
    (void)hi;
    auto sw = __builtin_amdgcn_permlane32_swap(a, b, false, false);
    ret0 = sw[0]; ret1 = sw[1];
#else
    u32 pa = __shfl_xor(a, 32), pb = __shfl_xor(b, 32);
    ret0 = hi ? pb : a;
    ret1 = hi ? b : pa;
#endif
}

// ---- Kernel 1: partial GN stats. 1536 blocks = 8 channel-octet slices per
// (b,group); partials[blk*2 + {0,1}] = {sum, sumsq} of 8192 floats.
__global__ __launch_bounds__(256) void gn_partial(const float* __restrict__ x,
                                                  float* __restrict__ partials) {
    int blk = blockIdx.x;
    const float4* p = (const float4*)(x + (size_t)blk * 8192);
    int t = threadIdx.x;
    float s1a = 0.f, s2a = 0.f, s1b = 0.f, s2b = 0.f;
#pragma unroll
    for (int i = 0; i < 8; i += 2) {
        float4 va = p[t + i * 256];
        float4 vb = p[t + (i + 1) * 256];
        s1a += va.x + va.y + va.z + va.w;
        s2a += va.x*va.x + va.y*va.y + va.z*va.z + va.w*va.w;
        s1b += vb.x + vb.y + vb.z + vb.w;
        s2b += vb.x*vb.x + vb.y*vb.y + vb.z*vb.z + vb.w*vb.w;
    }
    float s1 = s1a + s1b, s2 = s2a + s2b;
    for (int off = 32; off > 0; off >>= 1) {
        s1 += __shfl_down(s1, off);
        s2 += __shfl_down(s2, off);
    }
    __shared__ float a1[4], a2[4];
    int wave = t >> 6, lane = t & 63;
    if (lane == 0) { a1[wave] = s1; a2[wave] = s2; }
    __syncthreads();
    if (t == 0) {
        partials[blk * 2 + 0] = a1[0] + a1[1] + a1[2] + a1[3];
        partials[blk * 2 + 1] = a2[0] + a2[1] + a2[2] + a2[3];
    }
}

__device__ __forceinline__ void group_stats(const float* __restrict__ partials,
                                            int bg, float& mean, float& rstd) {
    float s1 = 0.f, s2 = 0.f;
#pragma unroll
    for (int j = 0; j < 8; ++j) {
        s1 += partials[(bg * 8 + j) * 2 + 0];
        s2 += partials[(bg * 8 + j) * 2 + 1];
    }
    mean = s1 * (1.f / 65536.f);
    float var = s2 * (1.f / 65536.f) - mean * mean;
    rstd = rsqrtf(var + 1e-5f);
}

// ---- Kernel 2: fused normalize+pack+flash-attention.
// Grid 512: bid = qt*64 + pair -> bid%8 = pair%8: all 8 qt-blocks of a pair
// share an XCD (their 8x re-read of the pair's K/V x-channels is L2-local).
// Block = 256 thr = 4 waves; block owns 128 queries (32/wave).
// Staging: per K-tile (64 keys), raw x K/V channels are loaded to registers
// early (prefetch under compute), then normalized+packed (pack2 -> bf16) and
// ds_written into XOR-swizzled KT/VT identical in layout to the old Kn/Vn
// staging, so the MFMA read side is unchanged from the verified kernel:
//   KT row = key (64), 8 uint4 chunks = channels (chunk^(row&7) swizzle)
//   VT row = v-channel (64), 8 uint4 chunks = 8 keys each (same swizzle)
// Thread staging geometry: sr = tid&63, cc0 = tid>>6.
//   K: rows sr, chunks {cc0, cc0+4} (channels cc*8..+8) -> 16 scalar x loads
//      (lane sr contiguous in s: coalesced 256B per channel).
//   V: channel sr, s-range cc0*16..+16 -> 4 float4 x loads (64B/lane).
// Q: packed once in prologue from raw x (coalesced scalar loads).
__global__ __launch_bounds__(256, 2) void attn_fused(
    const float* __restrict__ x, const float* __restrict__ gamma,
    const float* __restrict__ beta, const float* __restrict__ partials,
    float* __restrict__ out)
{
    const int bid = blockIdx.x;
    const int qt = bid >> 6;        // 0..7
    const int pair = bid & 63;
    const int b = pair >> 3, h = pair & 7;
    const float* xb = x + (size_t)b * 1536 * 1024;
    const int tid = threadIdx.x;
    const int w = tid >> 6;
    const int lane = tid & 63;
    const int li = lane & 31;       // q within wave tile
    const int hi = lane >> 5;

    float ms[3], rs[3];
    group_stats(partials, b * 24 + 3 * h + 0, ms[0], rs[0]);
    group_stats(partials, b * 24 + 3 * h + 1, ms[1], rs[1]);
    group_stats(partials, b * 24 + 3 * h + 2, ms[2], rs[2]);

    __shared__ uint4 KT[2][512];            // [buf][row*8 + (chunk^(row&7))]
    __shared__ uint4 VT[2][512];

    // ---- staging geometry + per-thread channel params (held in regs)
    const int sr = tid & 63;                // K row (key) / V channel
    const int cc0 = tid >> 6;               // 0..3
    float kw[16], kb[16];
#pragma unroll
    for (int u = 0; u < 16; ++u) {
        int c = ((u < 8) ? cc0 : (cc0 + 4)) * 8 + (u & 7);
        int cg = h * 192 + c;
        kw[u] = gamma[cg] * rs[0];
        kb[u] = beta[cg] - ms[0] * kw[u];
    }
    const int vcg = h * 192 + 128 + sr;
    const float vw = gamma[vcg] * rs[2];
    const float vb = beta[vcg] - ms[2] * vw;

    const int kx = sr & 7;
    const int kidx0 = sr * 8 + (cc0 ^ kx);
    const int kidx1 = sr * 8 + ((cc0 + 4) ^ kx);
    const int vidx0 = sr * 8 + ((cc0 * 2) ^ kx);
    const int vidx1 = sr * 8 + ((cc0 * 2 + 1) ^ kx);

    const float* kbase = xb + (size_t)(h * 192) * 1024 + sr;   // + c*1024 + kt*64
    const float* vbase = xb + (size_t)vcg * 1024 + cc0 * 16;   // + kt*64

    // ---- Q: normalize+pack into B-frags B[n=q=li][k=c = cs*16+hi*8+j]
    const int q0 = qt * 128 + w * 32;
    bf16x8 bq[4];
#pragma unroll
    for (int cs = 0; cs < 4; ++cs) {
        u32 qq[4];
#pragma unroll
        for (int jp = 0; jp < 4; ++jp) {
            int cg = h * 192 + 64 + cs * 16 + hi * 8 + jp * 2;
            float w0 = gamma[cg] * rs[1],     b0 = beta[cg] - ms[1] * w0;
            float w1 = gamma[cg + 1] * rs[1], b1 = beta[cg + 1] - ms[1] * w1;
            float a0 = xb[(size_t)cg * 1024 + q0 + li];
            float a1 = xb[(size_t)(cg + 1) * 1024 + q0 + li];
            qq[jp] = pack2(__builtin_fmaf(a0, w0, b0), __builtin_fmaf(a1, w1, b1));
        }
        BB tb; tb.u = uint4{qq[0], qq[1], qq[2], qq[3]};
        bq[cs] = tb.v;
    }

    f32x16 oacc[2];
    oacc[0] = zero16(); oacc[1] = zero16();
    float lsum = 0.f;

    const int x7 = li & 7;                  // (row&7) for MFMA-side LDS reads

    // ---- staging load (raw f32 -> regs) and commit (normalize+pack+ds_write)
    float rk[16], rv[16];
#define LOAD_TILE(KT_)                                                        \
    {                                                                         \
        const float* kp = kbase + (KT_) * 64;                                 \
        _Pragma("unroll")                                                     \
        for (int u = 0; u < 16; ++u) {                                        \
            int c = ((u < 8) ? cc0 : (cc0 + 4)) * 8 + (u & 7);                \
            rk[u] = kp[(size_t)c * 1024];                                     \
        }                                                                     \
        const float* vp = vbase + (KT_) * 64;                                 \
        _Pragma("unroll")                                                     \
        for (int f = 0; f < 4; ++f) {                                         \
            float4 vq = *(const float4*)(vp + f * 4);                         \
            rv[f * 4 + 0] = vq.x; rv[f * 4 + 1] = vq.y;                       \
            rv[f * 4 + 2] = vq.z; rv[f * 4 + 3] = vq.w;                       \
        }                                                                     \
    }
#define COMMIT_TILE(BUF_)                                                     \
    {                                                                         \
        uint4 ka, kc, va, vc;                                                 \
        ka.x = pack2(__builtin_fmaf(rk[0], kw[0], kb[0]),                     \
                     __builtin_fmaf(rk[1], kw[1], kb[1]));                    \
        ka.y = pack2(__builtin_fmaf(rk[2], kw[2], kb[2]),                     \
                     __builtin_fmaf(rk[3], kw[3], kb[3]));                    \
        ka.z = pack2(__builtin_fmaf(rk[4], kw[4], kb[4]),                     \
                     __builtin_fmaf(rk[5], kw[5], kb[5]));                    \
        ka.w = pack2(__builtin_fmaf(rk[6], kw[6], kb[6]),                     \
                     __builtin_fmaf(rk[7], kw[7], kb[7]));                    \
        kc.x = pack2(__builtin_fmaf(rk[8], kw[8], kb[8]),                     \
                     __builtin_fmaf(rk[9], kw[9], kb[9]));                    \
        kc.y = pack2(__builtin_fmaf(rk[10], kw[10], kb[10]),                  \
                     __builtin_fmaf(rk[11], kw[11], kb[11]));                 \
        kc.z = pack2(__builtin_fmaf(rk[12], kw[12], kb[12]),                  \
                     __builtin_fmaf(rk[13], kw[13], kb[13]));                 \
        kc.w = pack2(__builtin_fmaf(rk[14], kw[14], kb[14]),                  \
                     __builtin_fmaf(rk[15], kw[15], kb[15]));                 \
        va.x = pack2(__builtin_fmaf(rv[0], vw, vb),                           \
                     __builtin_fmaf(rv[1], vw, vb));                          \
        va.y = pack2(__builtin_fmaf(rv[2], vw, vb),                           \
                     __builtin_fmaf(rv[3], vw, vb));                          \
        va.z = pack2(__builtin_fmaf(rv[4], vw, vb),                           \
                     __builtin_fmaf(rv[5], vw, vb));                          \
        va.w = pack2(__builtin_fmaf(rv[6], vw, vb),                           \
                     __builtin_fmaf(rv[7], vw, vb));                          \
        vc.x = pack2(__builtin_fmaf(rv[8], vw, vb),                           \
                     __builtin_fmaf(rv[9], vw, vb));                          \
        vc.y = pack2(__builtin_fmaf(rv[10], vw, vb),                          \
                     __builtin_fmaf(rv[11], vw, vb));                         \
        vc.z = pack2(__builtin_fmaf(rv[12], vw, vb),                          \
                     __builtin_fmaf(rv[13], vw, vb));                         \
        vc.w = pack2(__builtin_fmaf(rv[14], vw, vb),                          \
                     __builtin_fmaf(rv[15], vw, vb));                         \
        KT[BUF_][kidx0] = ka; KT[BUF_][kidx1] = kc;                           \
        VT[BUF_][vidx0] = va; VT[BUF_][vidx1] = vc;                           \
    }

    // ---- prologue: stage tile 0
    LOAD_TILE(0);
    COMMIT_TILE(0);
    __syncthreads();

#pragma unroll 2
    for (int kt = 0; kt < 16; ++kt) {
        const int cur = kt & 1;
        // ---- issue next tile's raw loads (covered by this tile's compute)
        if (kt < 15) LOAD_TILE(kt + 1);

        // ---- S^T = K Q^T : 2 key-blocks of 32, accumulate over 4 c-steps
        f32x16 sf[2];
#pragma unroll
        for (int kf = 0; kf < 2; ++kf) {
            bf16x8 ak[4];
#pragma unroll
            for (int cs = 0; cs < 4; ++cs)
                ak[cs] = ((const BB*)&KT[cur][(kf * 32 + li) * 8 + ((cs * 2 + hi) ^ x7)])->v;
            f32x16 acc = zero16();
            __builtin_amdgcn_s_setprio(1);
#pragma unroll
            for (int cs = 0; cs < 4; ++cs)
                acc = __builtin_amdgcn_mfma_f32_32x32x16_bf16(ak[cs], bq[cs], acc, 0, 0, 0);
            __builtin_amdgcn_s_setprio(0);
            sf[kf] = acc;
        }

        // ---- P = exp2(s*scale - OFF); pack + partner swap -> PV B-frags.
        BB pbv[4];
#pragma unroll
        for (int kf = 0; kf < 2; ++kf)
#pragma unroll
            for (int s = 0; s < 2; ++s) {
                float p0 = exp2f(__builtin_fmaf(sf[kf][8 * s + 0], SM_SCALE, -SM_OFF));
                float p1 = exp2f(__builtin_fmaf(sf[kf][8 * s + 1], SM_SCALE, -SM_OFF));
                float p2 = exp2f(__builtin_fmaf(sf[kf][8 * s + 2], SM_SCALE, -SM_OFF));
                float p3 = exp2f(__builtin_fmaf(sf[kf][8 * s + 3], SM_SCALE, -SM_OFF));
                float p4 = exp2f(__builtin_fmaf(sf[kf][8 * s + 4], SM_SCALE, -SM_OFF));
                float p5 = exp2f(__builtin_fmaf(sf[kf][8 * s + 5], SM_SCALE, -SM_OFF));
                float p6 = exp2f(__builtin_fmaf(sf[kf][8 * s + 6], SM_SCALE, -SM_OFF));
                float p7 = exp2f(__builtin_fmaf(sf[kf][8 * s + 7], SM_SCALE, -SM_OFF));
                lsum += ((p0 + p1) + (p2 + p3)) + ((p4 + p5) + (p6 + p7));
                u32 Pa = pack2(p0, p1), Pb = pack2(p2, p3);
                u32 Pc = pack2(p4, p5), Pd = pack2(p6, p7);
                u32 w0, w1, w2, w3;
                swap32(Pa, Pc, hi, w0, w2);   // w0=offs 8hi+{0,1}, w2=8hi+{4,5}
                swap32(Pb, Pd, hi, w1, w3);   // w1=offs 8hi+{2,3}, w3=8hi+{6,7}
                pbv[kf * 2 + s].u = uint4{w0, w1, w2, w3};
            }

        // ---- O^T += V P : A=V[m=v][k=key] (2 vf x 4 ks), B=P
#pragma unroll
        for (int vf = 0; vf < 2; ++vf) {
            bf16x8 av[4];
#pragma unroll
            for (int ks = 0; ks < 4; ++ks)
                av[ks] = ((const BB*)&VT[cur][(vf * 32 + li) * 8 + ((ks * 2 + hi) ^ x7)])->v;
            __builtin_amdgcn_s_setprio(1);
#pragma unroll
            for (int ks = 0; ks < 4; ++ks)
                oacc[vf] = __builtin_amdgcn_mfma_f32_32x32x16_bf16(av[ks], pbv[ks].v, oacc[vf], 0, 0, 0);
            __builtin_amdgcn_s_setprio(0);
        }

        // ---- commit staged tile (normalize+pack+write), one barrier per iter
        if (kt < 15) COMMIT_TILE(cur ^ 1);
        __syncthreads();
    }

    // ---- epilogue: l covers own hi-half key offsets; partner holds the rest.
    lsum += __shfl_xor(lsum, 32);
    float invl = 1.f / lsum;
    float* ob = out + (size_t)pair * 65536 + q0 + li;
#pragma unroll
    for (int vf = 0; vf < 2; ++vf)
#pragma unroll
        for (int r = 0; r < 16; ++r) {
            int v = vf * 32 + (r & 3) + 8 * (r >> 2) + 4 * hi;
            ob[(size_t)v * 1024] = oacc[vf][r] * invl;
        }
}

extern "C" void kernel_launch(void* const* d_in, const int* in_sizes, int n_in,
                              void* d_out, int out_size, void* d_ws, size_t ws_size,
                              hipStream_t stream) {
    const float* x     = (const float*)d_in[0];
    const float* gamma = (const float*)d_in[1];
    const float* beta  = (const float*)d_in[2];
    float* out = (float*)d_out;

    float* partials = (float*)d_ws;                       // 3072 f32

    gn_partial<<<1536, 256, 0, stream>>>(x, partials);
    attn_fused<<<512, 256, 0, stream>>>(x, gamma, beta, partials, out);
}